// Round 8
// baseline (151.409 us; speedup 1.0000x reference)
//
#include <hip/hip_runtime.h>

#define A_ 4096
#define M_ 64
#define Q_ 64
#define H_ 128

// ws layout (floats): partials [3][A_] @0 (48 KB); counter (int) right after.

// ---------------------------------------------------------------------------
// Monolithic kernel: one block (256 thr) per atom, fused final reduce.
//  * phase 0: explicit 12x float4 register burst of the whole 48KB gradient
//    block, pinned with sched_barrier(0) so the compiler cannot sink it
//    (R6 failure mode: no pins -> loads sunk, VGPR 56, 151us; R7 proved the
//    pins hold the burst through an epilogue change)
//  * W0[z] in registers (8x float4/thread, one coalesced L2 pass)
//  * coef (minimum-image rij^2 * mask^2) on wave 1, parallel to staging
//  * fwd/bwd MLP via conflict-free LDS partial-sum matrices, all 256 threads
//  * element-separable dipole accumulation; per-wave shfl butterfly epilogue
//  * last-finishing block (threadfence + atomicAdd rendezvous) does the
//    deterministic fixed-order final reduce partials[3][A] -> out[3]
// ---------------------------------------------------------------------------
__global__ __launch_bounds__(256, 4) void tnep_fused(
    const float* __restrict__ desc,     // [A,Q]
    const float* __restrict__ grad,     // [A,M,3,Q]
    const int*   __restrict__ gidx,     // [A,M]
    const float* __restrict__ pos,      // [A,3]
    const int*   __restrict__ Zt,       // [A]
    const float* __restrict__ box,      // [3,3]
    const float* __restrict__ amask,    // [A]
    const float* __restrict__ nmask,    // [A,M]
    const float* __restrict__ W0,       // [NT,Q,H]
    const float* __restrict__ b0,       // [NT,H]
    const float* __restrict__ W1,       // [NT,H]
    float* __restrict__ partials,       // [3][A]  c-major
    int*   __restrict__ counter,        // zeroed via hipMemsetAsync
    float* __restrict__ out)            // [3]
{
    __shared__ __align__(16) float desc_s[Q_];
    __shared__ __align__(16) float dedq_s[Q_];
    __shared__ float coef_s[M_];
    __shared__ float psumF[8 * 132];            // [qgroup][h], pad 132
    __shared__ __align__(16) float deda_s[H_];
    __shared__ float psumB[Q_ * 33];            // [q][hgroup], pad 33
    __shared__ float wred[3][4];                // per-wave partial dipole
    __shared__ float fred[3][256];              // final-reduce scratch
    __shared__ int   last_s;

    const int n = blockIdx.x;
    const int t = threadIdx.x;

    // ---- phase 0: issue the 48KB gradient burst FIRST ----
    const float4* gbase = (const float4*)(grad + (size_t)n * (M_ * 3 * Q_));
    float4 gpre[12];
    #pragma unroll
    for (int i = 0; i < 12; ++i) gpre[i] = gbase[i * 256 + t];
    // pin: nothing may be scheduled across this point; burst stays issued
    // here (loads in flight), cannot be sunk past the barriers below.
    __builtin_amdgcn_sched_barrier(0);

    const int z = Zt[n];

    // ---- W0[z] -> registers: chunk t+256k => q=(t>>5)+8k, h0=4*(t&31) ----
    const float4* W0z4 = (const float4*)(W0 + (size_t)z * (Q_ * H_));
    float4 w0r[8];
    #pragma unroll
    for (int k = 0; k < 8; ++k) w0r[k] = W0z4[t + 256 * k];
    __builtin_amdgcn_sched_barrier(0);

    if (t < 16) ((float4*)desc_s)[t] = ((const float4*)(desc + n * Q_))[t];

    // ---- wave 1: minimum-image coef[m] = -rij2 * nmask^2 (independent) ----
    if (t >= 64 && t < 128) {
        int m = t - 64;
        float b00 = box[0], b01 = box[1], b02 = box[2];
        float b10 = box[3], b11 = box[4], b12 = box[5];
        float b20 = box[6], b21 = box[7], b22 = box[8];
        float c00 =   b11 * b22 - b12 * b21;
        float c01 = -(b10 * b22 - b12 * b20);
        float c02 =   b10 * b21 - b11 * b20;
        float det = b00 * c00 + b01 * c01 + b02 * c02;
        float id  = 1.0f / det;
        float i00 = c00 * id;
        float i10 = c01 * id;
        float i20 = c02 * id;
        float i01 = -(b01 * b22 - b02 * b21) * id;
        float i11 =  (b00 * b22 - b02 * b20) * id;
        float i21 = -(b00 * b21 - b01 * b20) * id;
        float i02 =  (b01 * b12 - b02 * b11) * id;
        float i12 = -(b00 * b12 - b02 * b10) * id;
        float i22 =  (b00 * b11 - b01 * b10) * id;

        int j = gidx[n * M_ + m];
        float dx = pos[j * 3 + 0] - pos[n * 3 + 0];
        float dy = pos[j * 3 + 1] - pos[n * 3 + 1];
        float dz = pos[j * 3 + 2] - pos[n * 3 + 2];
        float fx = dx * i00 + dy * i10 + dz * i20;
        float fy = dx * i01 + dy * i11 + dz * i21;
        float fz = dx * i02 + dy * i12 + dz * i22;
        fx -= rintf(fx); fy -= rintf(fy); fz -= rintf(fz);
        float rx = fx * b00 + fy * b10 + fz * b20;
        float ry = fx * b01 + fy * b11 + fz * b21;
        float rz = fx * b02 + fy * b12 + fz * b22;
        float nm = nmask[n * M_ + m];
        coef_s[m] = -((rx * rx + ry * ry + rz * rz) * nm) * nm;
    }
    __syncthreads();

    // ---- fwd partials: pre[h] = sum_q desc[q]*W0[q][h] (k-reduced in regs) ----
    {
        const int g = t >> 5;
        const int hbase = (t & 31) * 4;
        float fx = 0.f, fy = 0.f, fz = 0.f, fw = 0.f;
        #pragma unroll
        for (int k = 0; k < 8; ++k) {
            float d = desc_s[g + 8 * k];
            float4 w = w0r[k];
            fx += d * w.x; fy += d * w.y; fz += d * w.z; fw += d * w.w;
        }
        psumF[g * 132 + hbase + 0] = fx;
        psumF[g * 132 + hbase + 1] = fy;
        psumF[g * 132 + hbase + 2] = fz;
        psumF[g * 132 + hbase + 3] = fw;
    }
    __syncthreads();

    if (t < H_) {
        float pre = b0[z * H_ + t];
        #pragma unroll
        for (int g = 0; g < 8; ++g) pre += psumF[g * 132 + t];
        float am = amask[n];
        float hv = tanhf(pre) * am;
        deda_s[t] = (1.0f - hv * hv) * W1[z * H_ + t];
    }
    __syncthreads();

    // ---- bwd partials: dedq[q] = sum_h deda[h]*W0[q][h] ----
    {
        float4 dd = ((const float4*)deda_s)[t & 31];
        #pragma unroll
        for (int k = 0; k < 8; ++k) {
            int q = (t >> 5) + 8 * k;
            float4 w = w0r[k];
            psumB[q * 33 + (t & 31)] =
                w.x * dd.x + w.y * dd.y + w.z * dd.z + w.w * dd.w;
        }
    }
    __syncthreads();

    if (t < Q_) {
        float s = 0.0f;
        #pragma unroll
        for (int v = 0; v < 32; ++v) s += psumB[t * 33 + v];
        dedq_s[t] = s;
    }
    __syncthreads();

    // ---- consume prefetched gradients, element-separable dipole ----
    float a0 = 0.f, a1 = 0.f, a2 = 0.f;
    const float4* dq4 = (const float4*)dedq_s;
    #pragma unroll
    for (int i = 0; i < 12; ++i) {
        int idx = i * 256 + t;               // f4 index in [0, 3072)
        int m   = idx / 48;
        int rc  = idx - m * 48;
        int c   = rc >> 4;
        int q4  = rc & 15;
        float4 g = gpre[i];
        float4 d = dq4[q4];
        float  p = (g.x * d.x + g.y * d.y + g.z * d.z + g.w * d.w) * coef_s[m];
        a0 += (c == 0) ? p : 0.0f;
        a1 += (c == 1) ? p : 0.0f;
        a2 += (c == 2) ? p : 0.0f;
    }

    // ---- per-wave shfl butterfly (fixed order, deterministic, no barriers) ----
    #pragma unroll
    for (int off = 32; off > 0; off >>= 1) {
        a0 += __shfl_down(a0, off);
        a1 += __shfl_down(a1, off);
        a2 += __shfl_down(a2, off);
    }
    if ((t & 63) == 0) {
        int w = t >> 6;
        wred[0][w] = a0; wred[1][w] = a1; wred[2][w] = a2;
    }
    __syncthreads();

    if (t == 0) {
        partials[n]          = (wred[0][0] + wred[0][1]) + (wred[0][2] + wred[0][3]);
        partials[A_ + n]     = (wred[1][0] + wred[1][1]) + (wred[1][2] + wred[1][3]);
        partials[2 * A_ + n] = (wred[2][0] + wred[2][1]) + (wred[2][2] + wred[2][3]);
        __threadfence();                      // publish partials
        int old = atomicAdd(counter, 1);
        last_s = (old == A_ - 1) ? 1 : 0;
    }
    __syncthreads();

    // ---- last-finishing block: deterministic fixed-order final reduce ----
    if (last_s) {
        __threadfence();                      // acquire all partials
        const float4* p0 = (const float4*)(partials);
        const float4* p1 = (const float4*)(partials + A_);
        const float4* p2 = (const float4*)(partials + 2 * A_);
        float s0 = 0.f, s1 = 0.f, s2 = 0.f;
        #pragma unroll
        for (int k = 0; k < 4; ++k) {
            int i = k * 256 + t;
            float4 a = p0[i]; s0 += (a.x + a.y) + (a.z + a.w);
            float4 b = p1[i]; s1 += (b.x + b.y) + (b.z + b.w);
            float4 c = p2[i]; s2 += (c.x + c.y) + (c.z + c.w);
        }
        fred[0][t] = s0; fred[1][t] = s1; fred[2][t] = s2;
        __syncthreads();
        #pragma unroll
        for (int off = 128; off > 0; off >>= 1) {
            if (t < off) {
                fred[0][t] += fred[0][t + off];
                fred[1][t] += fred[1][t + off];
                fred[2][t] += fred[2][t + off];
            }
            __syncthreads();
        }
        if (t == 0) { out[0] = fred[0][0]; out[1] = fred[1][0]; out[2] = fred[2][0]; }
    }
}

extern "C" void kernel_launch(void* const* d_in, const int* in_sizes, int n_in,
                              void* d_out, int out_size, void* d_ws, size_t ws_size,
                              hipStream_t stream) {
    const float* desc  = (const float*)d_in[0];
    const float* grad  = (const float*)d_in[1];
    const int*   gidx  = (const int*)  d_in[2];
    const float* pos   = (const float*)d_in[3];
    const int*   Zt    = (const int*)  d_in[4];
    const float* box   = (const float*)d_in[5];
    const float* amask = (const float*)d_in[6];
    const float* nmask = (const float*)d_in[7];
    const float* W0    = (const float*)d_in[8];
    const float* b0    = (const float*)d_in[9];
    const float* W1    = (const float*)d_in[10];
    // d_in[11] = b1 (unused for the dipole output)

    float* partials = (float*)d_ws;                    // [3][A] = 48 KB
    int*   counter  = (int*)((float*)d_ws + 3 * A_);   // 1 int
    float* out      = (float*)d_out;                   // 3 floats

    hipMemsetAsync(counter, 0, sizeof(int), stream);   // rendezvous reset
    tnep_fused<<<A_, 256, 0, stream>>>(desc, grad, gidx, pos, Zt, box,
                                       amask, nmask, W0, b0, W1,
                                       partials, counter, out);
}

// Round 9
// 48.234 us; speedup vs baseline: 3.1390x; 3.1390x over previous
//
#include <hip/hip_runtime.h>

#define A_ 4096
#define M_ 64
#define Q_ 64
#define H_ 128

// ws layout (floats): dedq [A_*Q_] @0 ; coef [A_*M_] @A_*Q_ ;
//                     partials [3][A_] @2*A_*Q_.

// ---------------------------------------------------------------------------
// Kernel A (R3-proven): per-atom MLP fwd+bwd -> dedq, minimum-image coef.
// W0[z] in registers (8x float4/thread, one coalesced L2 pass).
// ---------------------------------------------------------------------------
__global__ __launch_bounds__(256) void tnep_mlp(
    const float* __restrict__ desc,     // [A,Q]
    const int*   __restrict__ gidx,     // [A,M]
    const float* __restrict__ pos,      // [A,3]
    const int*   __restrict__ Zt,       // [A]
    const float* __restrict__ box,      // [3,3]
    const float* __restrict__ amask,    // [A]
    const float* __restrict__ nmask,    // [A,M]
    const float* __restrict__ W0,       // [NT,Q,H]
    const float* __restrict__ b0,       // [NT,H]
    const float* __restrict__ W1,       // [NT,H]
    float* __restrict__ dedq_g,         // [A,Q]
    float* __restrict__ coef_g)         // [A,M]
{
    __shared__ __align__(16) float desc_s[Q_];
    __shared__ float psumF[8 * 132];            // [qgroup][h]
    __shared__ __align__(16) float deda_s[H_];
    __shared__ float psumB[Q_ * 33];            // [q][hgroup], pad 33

    const int n = blockIdx.x;
    const int t = threadIdx.x;
    const int z = Zt[n];

    // --- W0[z] -> registers: chunk t+256k => q=(t>>5)+8k, h0=4*(t&31) ---
    const float4* W0z4 = (const float4*)(W0 + (size_t)z * (Q_ * H_));
    float4 w0r[8];
    #pragma unroll
    for (int k = 0; k < 8; ++k) w0r[k] = W0z4[t + 256 * k];

    if (t < 16) ((float4*)desc_s)[t] = ((const float4*)(desc + n * Q_))[t];

    // --- wave 1: minimum-image coef[m] = -rij2 * nmask^2 (independent) ---
    if (t >= 64 && t < 128) {
        int m = t - 64;
        float b00 = box[0], b01 = box[1], b02 = box[2];
        float b10 = box[3], b11 = box[4], b12 = box[5];
        float b20 = box[6], b21 = box[7], b22 = box[8];
        float c00 =   b11 * b22 - b12 * b21;
        float c01 = -(b10 * b22 - b12 * b20);
        float c02 =   b10 * b21 - b11 * b20;
        float det = b00 * c00 + b01 * c01 + b02 * c02;
        float id  = 1.0f / det;
        float i00 = c00 * id;
        float i10 = c01 * id;
        float i20 = c02 * id;
        float i01 = -(b01 * b22 - b02 * b21) * id;
        float i11 =  (b00 * b22 - b02 * b20) * id;
        float i21 = -(b00 * b21 - b01 * b20) * id;
        float i02 =  (b01 * b12 - b02 * b11) * id;
        float i12 = -(b00 * b12 - b02 * b10) * id;
        float i22 =  (b00 * b11 - b01 * b10) * id;

        int j = gidx[n * M_ + m];
        float dx = pos[j * 3 + 0] - pos[n * 3 + 0];
        float dy = pos[j * 3 + 1] - pos[n * 3 + 1];
        float dz = pos[j * 3 + 2] - pos[n * 3 + 2];
        float fx = dx * i00 + dy * i10 + dz * i20;
        float fy = dx * i01 + dy * i11 + dz * i21;
        float fz = dx * i02 + dy * i12 + dz * i22;
        fx -= rintf(fx); fy -= rintf(fy); fz -= rintf(fz);
        float rx = fx * b00 + fy * b10 + fz * b20;
        float ry = fx * b01 + fy * b11 + fz * b21;
        float rz = fx * b02 + fy * b12 + fz * b22;
        float nm = nmask[n * M_ + m];
        coef_g[n * M_ + m] = -((rx * rx + ry * ry + rz * rz) * nm) * nm;
    }
    __syncthreads();

    // --- fwd partials: pre[h] = sum_q desc[q]*W0[q][h] (k-reduced in regs) ---
    {
        const int g = t >> 5;
        const int hbase = (t & 31) * 4;
        float fx = 0.f, fy = 0.f, fz = 0.f, fw = 0.f;
        #pragma unroll
        for (int k = 0; k < 8; ++k) {
            float d = desc_s[g + 8 * k];
            float4 w = w0r[k];
            fx += d * w.x; fy += d * w.y; fz += d * w.z; fw += d * w.w;
        }
        psumF[g * 132 + hbase + 0] = fx;
        psumF[g * 132 + hbase + 1] = fy;
        psumF[g * 132 + hbase + 2] = fz;
        psumF[g * 132 + hbase + 3] = fw;
    }
    __syncthreads();

    if (t < H_) {
        float pre = b0[z * H_ + t];
        #pragma unroll
        for (int g = 0; g < 8; ++g) pre += psumF[g * 132 + t];
        float am = amask[n];
        float hv = tanhf(pre) * am;
        deda_s[t] = (1.0f - hv * hv) * W1[z * H_ + t];
    }
    __syncthreads();

    // --- bwd partials: dedq[q] = sum_h deda[h]*W0[q][h] ---
    {
        float4 dd = ((const float4*)deda_s)[t & 31];
        #pragma unroll
        for (int k = 0; k < 8; ++k) {
            int q = (t >> 5) + 8 * k;
            float4 w = w0r[k];
            psumB[q * 33 + (t & 31)] =
                w.x * dd.x + w.y * dd.y + w.z * dd.z + w.w * dd.w;
        }
    }
    __syncthreads();

    if (t < Q_) {
        float s = 0.0f;
        #pragma unroll
        for (int v = 0; v < 32; ++v) s += psumB[t * 33 + v];
        dedq_g[n * Q_ + t] = s;
    }
}

// ---------------------------------------------------------------------------
// Kernel B: PURE stream. One atom per block; 12x float4 pinned register
// burst; tiny LDS stage; one barrier; consume; per-wave shfl butterfly.
// No MLP on the critical path -> 6 blocks/CU (launch_bounds 256,6),
// ~288KB reads in flight per CU, near-100% stream duty cycle.
// ---------------------------------------------------------------------------
__global__ __launch_bounds__(256, 6) void tnep_stream(
    const float* __restrict__ grad,     // [A,M,3,Q]
    const float* __restrict__ dedq_g,   // [A,Q]
    const float* __restrict__ coef_g,   // [A,M]
    float* __restrict__ partials)       // [3][A]
{
    __shared__ __align__(16) float4 dedq_s[16];
    __shared__ __align__(16) float  coef_s[M_];
    __shared__ float wred[3][4];

    const int n = blockIdx.x;
    const int t = threadIdx.x;

    // ---- issue the 48KB gradient burst FIRST, pinned ----
    const float4* gbase = (const float4*)(grad + (size_t)n * (M_ * 3 * Q_));
    float4 gpre[12];
    #pragma unroll
    for (int i = 0; i < 12; ++i) gpre[i] = gbase[i * 256 + t];
    __builtin_amdgcn_sched_barrier(0);   // burst may not be sunk/split

    if (t < 16)       dedq_s[t] = ((const float4*)(dedq_g + n * Q_))[t];
    else if (t < 32)  ((float4*)coef_s)[t - 16] =
                          ((const float4*)(coef_g + n * M_))[t - 16];
    __syncthreads();

    // ---- consume: element-separable dipole ----
    float a0 = 0.f, a1 = 0.f, a2 = 0.f;
    const float4 d = dedq_s[t & 15];     // loop-invariant per thread
    #pragma unroll
    for (int i = 0; i < 12; ++i) {
        int idx = i * 256 + t;           // f4 index in [0, 3072)
        int m   = idx / 48;
        int rc  = idx - m * 48;
        int c   = rc >> 4;
        float4 g = gpre[i];
        float  p = (g.x * d.x + g.y * d.y + g.z * d.z + g.w * d.w) * coef_s[m];
        a0 += (c == 0) ? p : 0.0f;
        a1 += (c == 1) ? p : 0.0f;
        a2 += (c == 2) ? p : 0.0f;
    }

    // ---- per-wave shfl butterfly (fixed order, deterministic) ----
    #pragma unroll
    for (int off = 32; off > 0; off >>= 1) {
        a0 += __shfl_down(a0, off);
        a1 += __shfl_down(a1, off);
        a2 += __shfl_down(a2, off);
    }
    if ((t & 63) == 0) {
        int w = t >> 6;
        wred[0][w] = a0; wred[1][w] = a1; wred[2][w] = a2;
    }
    __syncthreads();

    if (t == 0) {
        partials[n]          = (wred[0][0] + wred[0][1]) + (wred[0][2] + wred[0][3]);
        partials[A_ + n]     = (wred[1][0] + wred[1][1]) + (wred[1][2] + wred[1][3]);
        partials[2 * A_ + n] = (wred[2][0] + wred[2][1]) + (wred[2][2] + wred[2][3]);
    }
}

// ---------------------------------------------------------------------------
// Final deterministic reduction: partials[3][A] -> out[3]. 1 block, 1024 thr.
// ---------------------------------------------------------------------------
__global__ __launch_bounds__(1024) void tnep_reduce(
    const float* __restrict__ partials, float* __restrict__ out)
{
    __shared__ float sb0[1024], sb1[1024], sb2[1024];
    const int t = threadIdx.x;
    const float4* p4 = (const float4*)partials;     // rows of 1024 f4
    float4 a = p4[t];
    float4 b = p4[1024 + t];
    float4 c = p4[2048 + t];
    sb0[t] = (a.x + a.y) + (a.z + a.w);
    sb1[t] = (b.x + b.y) + (b.z + b.w);
    sb2[t] = (c.x + c.y) + (c.z + c.w);
    __syncthreads();
    #pragma unroll
    for (int off = 512; off > 0; off >>= 1) {
        if (t < off) {
            sb0[t] += sb0[t + off];
            sb1[t] += sb1[t + off];
            sb2[t] += sb2[t + off];
        }
        __syncthreads();
    }
    if (t == 0) { out[0] = sb0[0]; out[1] = sb1[0]; out[2] = sb2[0]; }
}

extern "C" void kernel_launch(void* const* d_in, const int* in_sizes, int n_in,
                              void* d_out, int out_size, void* d_ws, size_t ws_size,
                              hipStream_t stream) {
    const float* desc  = (const float*)d_in[0];
    const float* grad  = (const float*)d_in[1];
    const int*   gidx  = (const int*)  d_in[2];
    const float* pos   = (const float*)d_in[3];
    const int*   Zt    = (const int*)  d_in[4];
    const float* box   = (const float*)d_in[5];
    const float* amask = (const float*)d_in[6];
    const float* nmask = (const float*)d_in[7];
    const float* W0    = (const float*)d_in[8];
    const float* b0    = (const float*)d_in[9];
    const float* W1    = (const float*)d_in[10];
    // d_in[11] = b1 (unused for the dipole output)

    float* ws       = (float*)d_ws;
    float* dedq_g   = ws;                          // A*Q = 1 MB
    float* coef_g   = ws + A_ * Q_;                // A*M = 1 MB
    float* partials = ws + 2 * A_ * Q_;            // [3][A] = 48 KB
    float* out      = (float*)d_out;               // 3 floats

    tnep_mlp<<<A_, 256, 0, stream>>>(desc, gidx, pos, Zt, box, amask, nmask,
                                     W0, b0, W1, dedq_g, coef_g);
    tnep_stream<<<A_, 256, 0, stream>>>(grad, dedq_g, coef_g, partials);
    tnep_reduce<<<1, 1024, 0, stream>>>(partials, out);
}

// Round 10
// 41.130 us; speedup vs baseline: 3.6813x; 1.1727x over previous
//
#include <hip/hip_runtime.h>

#define A_ 4096
#define M_ 64
#define Q_ 64
#define H_ 128

// ---------------------------------------------------------------------------
// R7 final (proven 41.6 us): monolithic kernel, one block (256 thr) per atom.
//  * phase 0: explicit 12x float4 register burst of the whole 48KB gradient
//    block; sched_barrier(0) pins the burst so the compiler cannot sink it
//    (R6/R8 failure mode: fused-reduce epilogue -> VGPR 56, loads sunk, 151us)
//  * W0[z] in registers (8x float4/thread, one coalesced L2 pass)
//  * coef (minimum-image rij^2 * mask^2) on wave 1, parallel to staging
//  * fwd/bwd MLP via conflict-free LDS partial-sum matrices, all 256 threads
//  * element-separable dipole accumulation; per-wave shfl butterfly epilogue
//  * separate 1-block reduce kernel (fusion via rendezvous is reproducibly
//    incompatible with the register burst: allocator drops to 56 VGPR)
// ---------------------------------------------------------------------------
__global__ __launch_bounds__(256, 4) void tnep_fused(
    const float* __restrict__ desc,     // [A,Q]
    const float* __restrict__ grad,     // [A,M,3,Q]
    const int*   __restrict__ gidx,     // [A,M]
    const float* __restrict__ pos,      // [A,3]
    const int*   __restrict__ Zt,       // [A]
    const float* __restrict__ box,      // [3,3]
    const float* __restrict__ amask,    // [A]
    const float* __restrict__ nmask,    // [A,M]
    const float* __restrict__ W0,       // [NT,Q,H]
    const float* __restrict__ b0,       // [NT,H]
    const float* __restrict__ W1,       // [NT,H]
    float* __restrict__ partials)       // [3][A]  c-major
{
    __shared__ __align__(16) float desc_s[Q_];
    __shared__ __align__(16) float dedq_s[Q_];
    __shared__ float coef_s[M_];
    __shared__ float psumF[8 * 132];            // [qgroup][h], pad 132
    __shared__ __align__(16) float deda_s[H_];
    __shared__ float psumB[Q_ * 33];            // [q][hgroup], pad 33
    __shared__ float wred[3][4];                // per-wave partial dipole

    const int n = blockIdx.x;
    const int t = threadIdx.x;

    // ---- phase 0: issue the 48KB gradient burst FIRST ----
    const float4* gbase = (const float4*)(grad + (size_t)n * (M_ * 3 * Q_));
    float4 gpre[12];
    #pragma unroll
    for (int i = 0; i < 12; ++i) gpre[i] = gbase[i * 256 + t];
    // pin: nothing may be scheduled across this point; burst stays issued
    // here (loads in flight), cannot be sunk past the barriers below.
    __builtin_amdgcn_sched_barrier(0);

    const int z = Zt[n];

    // ---- W0[z] -> registers: chunk t+256k => q=(t>>5)+8k, h0=4*(t&31) ----
    const float4* W0z4 = (const float4*)(W0 + (size_t)z * (Q_ * H_));
    float4 w0r[8];
    #pragma unroll
    for (int k = 0; k < 8; ++k) w0r[k] = W0z4[t + 256 * k];
    __builtin_amdgcn_sched_barrier(0);

    if (t < 16) ((float4*)desc_s)[t] = ((const float4*)(desc + n * Q_))[t];

    // ---- wave 1: minimum-image coef[m] = -rij2 * nmask^2 (independent) ----
    if (t >= 64 && t < 128) {
        int m = t - 64;
        float b00 = box[0], b01 = box[1], b02 = box[2];
        float b10 = box[3], b11 = box[4], b12 = box[5];
        float b20 = box[6], b21 = box[7], b22 = box[8];
        float c00 =   b11 * b22 - b12 * b21;
        float c01 = -(b10 * b22 - b12 * b20);
        float c02 =   b10 * b21 - b11 * b20;
        float det = b00 * c00 + b01 * c01 + b02 * c02;
        float id  = 1.0f / det;
        float i00 = c00 * id;
        float i10 = c01 * id;
        float i20 = c02 * id;
        float i01 = -(b01 * b22 - b02 * b21) * id;
        float i11 =  (b00 * b22 - b02 * b20) * id;
        float i21 = -(b00 * b21 - b01 * b20) * id;
        float i02 =  (b01 * b12 - b02 * b11) * id;
        float i12 = -(b00 * b12 - b02 * b10) * id;
        float i22 =  (b00 * b11 - b01 * b10) * id;

        int j = gidx[n * M_ + m];
        float dx = pos[j * 3 + 0] - pos[n * 3 + 0];
        float dy = pos[j * 3 + 1] - pos[n * 3 + 1];
        float dz = pos[j * 3 + 2] - pos[n * 3 + 2];
        float fx = dx * i00 + dy * i10 + dz * i20;
        float fy = dx * i01 + dy * i11 + dz * i21;
        float fz = dx * i02 + dy * i12 + dz * i22;
        fx -= rintf(fx); fy -= rintf(fy); fz -= rintf(fz);
        float rx = fx * b00 + fy * b10 + fz * b20;
        float ry = fx * b01 + fy * b11 + fz * b21;
        float rz = fx * b02 + fy * b12 + fz * b22;
        float nm = nmask[n * M_ + m];
        coef_s[m] = -((rx * rx + ry * ry + rz * rz) * nm) * nm;
    }
    __syncthreads();

    // ---- fwd partials: pre[h] = sum_q desc[q]*W0[q][h] (k-reduced in regs) ----
    {
        const int g = t >> 5;
        const int hbase = (t & 31) * 4;
        float fx = 0.f, fy = 0.f, fz = 0.f, fw = 0.f;
        #pragma unroll
        for (int k = 0; k < 8; ++k) {
            float d = desc_s[g + 8 * k];
            float4 w = w0r[k];
            fx += d * w.x; fy += d * w.y; fz += d * w.z; fw += d * w.w;
        }
        psumF[g * 132 + hbase + 0] = fx;
        psumF[g * 132 + hbase + 1] = fy;
        psumF[g * 132 + hbase + 2] = fz;
        psumF[g * 132 + hbase + 3] = fw;
    }
    __syncthreads();

    if (t < H_) {
        float pre = b0[z * H_ + t];
        #pragma unroll
        for (int g = 0; g < 8; ++g) pre += psumF[g * 132 + t];
        float am = amask[n];
        float hv = tanhf(pre) * am;
        deda_s[t] = (1.0f - hv * hv) * W1[z * H_ + t];
    }
    __syncthreads();

    // ---- bwd partials: dedq[q] = sum_h deda[h]*W0[q][h] ----
    {
        float4 dd = ((const float4*)deda_s)[t & 31];
        #pragma unroll
        for (int k = 0; k < 8; ++k) {
            int q = (t >> 5) + 8 * k;
            float4 w = w0r[k];
            psumB[q * 33 + (t & 31)] =
                w.x * dd.x + w.y * dd.y + w.z * dd.z + w.w * dd.w;
        }
    }
    __syncthreads();

    if (t < Q_) {
        float s = 0.0f;
        #pragma unroll
        for (int v = 0; v < 32; ++v) s += psumB[t * 33 + v];
        dedq_s[t] = s;
    }
    __syncthreads();

    // ---- consume prefetched gradients, element-separable dipole ----
    float a0 = 0.f, a1 = 0.f, a2 = 0.f;
    const float4* dq4 = (const float4*)dedq_s;
    #pragma unroll
    for (int i = 0; i < 12; ++i) {
        int idx = i * 256 + t;               // f4 index in [0, 3072)
        int m   = idx / 48;
        int rc  = idx - m * 48;
        int c   = rc >> 4;
        int q4  = rc & 15;
        float4 g = gpre[i];
        float4 d = dq4[q4];
        float  p = (g.x * d.x + g.y * d.y + g.z * d.z + g.w * d.w) * coef_s[m];
        a0 += (c == 0) ? p : 0.0f;
        a1 += (c == 1) ? p : 0.0f;
        a2 += (c == 2) ? p : 0.0f;
    }

    // ---- per-wave shfl butterfly (fixed order, deterministic, no barriers) ----
    #pragma unroll
    for (int off = 32; off > 0; off >>= 1) {
        a0 += __shfl_down(a0, off);
        a1 += __shfl_down(a1, off);
        a2 += __shfl_down(a2, off);
    }
    if ((t & 63) == 0) {
        int w = t >> 6;
        wred[0][w] = a0; wred[1][w] = a1; wred[2][w] = a2;
    }
    __syncthreads();

    if (t == 0) {
        partials[n]          = (wred[0][0] + wred[0][1]) + (wred[0][2] + wred[0][3]);
        partials[A_ + n]     = (wred[1][0] + wred[1][1]) + (wred[1][2] + wred[1][3]);
        partials[2 * A_ + n] = (wred[2][0] + wred[2][1]) + (wred[2][2] + wred[2][3]);
    }
}

// ---------------------------------------------------------------------------
// Final deterministic reduction: partials[3][A] -> out[3]. 1 block, 1024 thr.
// ---------------------------------------------------------------------------
__global__ __launch_bounds__(1024) void tnep_reduce(
    const float* __restrict__ partials, float* __restrict__ out)
{
    __shared__ float sb0[1024], sb1[1024], sb2[1024];
    const int t = threadIdx.x;
    const float4* p4 = (const float4*)partials;     // rows of 1024 f4
    float4 a = p4[t];
    float4 b = p4[1024 + t];
    float4 c = p4[2048 + t];
    sb0[t] = (a.x + a.y) + (a.z + a.w);
    sb1[t] = (b.x + b.y) + (b.z + b.w);
    sb2[t] = (c.x + c.y) + (c.z + c.w);
    __syncthreads();
    #pragma unroll
    for (int off = 512; off > 0; off >>= 1) {
        if (t < off) {
            sb0[t] += sb0[t + off];
            sb1[t] += sb1[t + off];
            sb2[t] += sb2[t + off];
        }
        __syncthreads();
    }
    if (t == 0) { out[0] = sb0[0]; out[1] = sb1[0]; out[2] = sb2[0]; }
}

extern "C" void kernel_launch(void* const* d_in, const int* in_sizes, int n_in,
                              void* d_out, int out_size, void* d_ws, size_t ws_size,
                              hipStream_t stream) {
    const float* desc  = (const float*)d_in[0];
    const float* grad  = (const float*)d_in[1];
    const int*   gidx  = (const int*)  d_in[2];
    const float* pos   = (const float*)d_in[3];
    const int*   Zt    = (const int*)  d_in[4];
    const float* box   = (const float*)d_in[5];
    const float* amask = (const float*)d_in[6];
    const float* nmask = (const float*)d_in[7];
    const float* W0    = (const float*)d_in[8];
    const float* b0    = (const float*)d_in[9];
    const float* W1    = (const float*)d_in[10];
    // d_in[11] = b1 (unused for the dipole output)

    float* partials = (float*)d_ws;      // [3][A] floats = 48 KB
    float* out      = (float*)d_out;     // 3 floats

    tnep_fused<<<A_, 256, 0, stream>>>(desc, grad, gidx, pos, Zt, box,
                                       amask, nmask, W0, b0, W1, partials);
    tnep_reduce<<<1, 1024, 0, stream>>>(partials, out);
}